// Round 1
// baseline (2056.389 us; speedup 1.0000x reference)
//
#include <hip/hip_runtime.h>
#include <hip/hip_bf16.h>
#include <hip/hip_cooperative_groups.h>

namespace cg = cooperative_groups;

typedef unsigned short u16;
typedef __attribute__((ext_vector_type(8))) short short8;
typedef __attribute__((ext_vector_type(4))) float f32x4;

#define NB 32      // trees
#define NN 128     // nodes per tree
#define HH 300     // hidden
#define G4 1200    // 4*H
#define NV 32000   // vocab
#define INW 350    // RD+E
#define KP 320     // padded K for MFMA (300 -> 320)

__device__ __forceinline__ float sigm(float x) { return 1.f / (1.f + __expf(-x)); }
__device__ __forceinline__ float tanh_f(float x) {
    float e = __expf(2.f * x);
    return 1.f - 2.f / (e + 1.f);
}

// h_buf/c_buf layout: [B][129][H]; slot 0 = root state
__global__ void k_init_roots(const float* __restrict__ rh, float* __restrict__ h_buf,
                             float* __restrict__ c_buf) {
    int n = blockIdx.x * blockDim.x + threadIdx.x;
    if (n < NB * HH) {
        int b = n / HH, u = n - b * HH;
        float v = rh[n];
        h_buf[(b * 129) * HH + u] = v;
        c_buf[(b * 129) * HH + u] = v;
    }
}

// WihT [350][1200], WhhT [300][1200]
__global__ void k_transpose(const float* __restrict__ W_ih, const float* __restrict__ W_hh,
                            float* __restrict__ WihT, float* __restrict__ WhhT) {
    const int tot = INW * G4 + HH * G4;
    for (int n = blockIdx.x * blockDim.x + threadIdx.x; n < tot; n += gridDim.x * blockDim.x) {
        if (n < INW * G4) {
            int c = n / G4, r = n - c * G4;
            WihT[n] = W_ih[r * INW + c];
        } else {
            int m = n - INW * G4;
            int c = m / G4, r = m - c * G4;
            WhhT[m] = W_hh[r * HH + c];
        }
    }
}

// xg[node][1200] = concat(rel_emb[rel], emb[word]) @ W_ih^T + b_ih
__global__ __launch_bounds__(256) void k_xg(const int* __restrict__ relations,
                                            const int* __restrict__ prev_words,
                                            const float* __restrict__ rel_emb,
                                            const float* __restrict__ emb,
                                            const float* __restrict__ WihT,
                                            const float* __restrict__ b_ih,
                                            float* __restrict__ xg) {
    __shared__ float xl[8][INW];
    __shared__ int rid[8], wid[8];
    const int tid = threadIdx.x;
    const int nb = blockIdx.x * 8;
    if (tid < 8) { rid[tid] = relations[nb + tid]; wid[tid] = prev_words[nb + tid]; }
    __syncthreads();
    for (int idx = tid; idx < 8 * INW; idx += 256) {
        int g = idx / INW, c = idx - g * INW;
        xl[g][c] = (c < 50) ? rel_emb[rid[g] * 50 + c] : emb[wid[g] * HH + (c - 50)];
    }
    __syncthreads();
    for (int k = 0; k < 5; ++k) {
        int r = k * 256 + tid;
        if (r >= G4) break;
        float acc[8] = {0.f, 0.f, 0.f, 0.f, 0.f, 0.f, 0.f, 0.f};
        for (int c = 0; c < INW; ++c) {
            float wv = WihT[(size_t)c * G4 + r];
#pragma unroll
            for (int g = 0; g < 8; ++g) acc[g] += wv * xl[g][c];
        }
        float bi = b_ih[r];
#pragma unroll
        for (int g = 0; g < 8; ++g) xg[(size_t)(nb + g) * G4 + r] = acc[g] + bi;
    }
}

// build level schedule: depth[], lvl_start[], lvl_cnt[], lvl_nodes[], nlev
__global__ void k_levels(const int* __restrict__ parents, int* __restrict__ depth,
                         int* __restrict__ lvl_start, int* __restrict__ lvl_cnt,
                         int* __restrict__ lvl_nodes, int* __restrict__ nlev) {
    __shared__ int cnt_s[128];
    __shared__ int cur_s[128];
    __shared__ int maxd_s;
    const int tid = threadIdx.x;
    if (tid < 128) cnt_s[tid] = 0;
    if (tid == 0) maxd_s = 0;
    __syncthreads();
    if (tid < NB) {
        int md = 0;
        for (int i = 0; i < NN; ++i) {
            int p = parents[tid * NN + i];
            int d = (p < 0) ? 0 : depth[tid * NN + p] + 1;
            depth[tid * NN + i] = d;
            atomicAdd(&cnt_s[d], 1);
            md = max(md, d);
        }
        atomicMax(&maxd_s, md);
    }
    __syncthreads();
    if (tid == 0) {
        int run = 0;
        for (int l = 0; l < 128; ++l) {
            lvl_start[l] = run;
            cur_s[l] = run;
            lvl_cnt[l] = cnt_s[l];
            run += cnt_s[l];
        }
        nlev[0] = maxd_s + 1;
    }
    __syncthreads();
    for (int n = tid; n < NB * NN; n += blockDim.x) {
        int slot = atomicAdd(&cur_s[depth[n]], 1);
        lvl_nodes[slot] = n;
    }
}

// cooperative level-parallel LSTM scan.
// Per level: MV phase (gates = xg + W_hh@ph + b_hh, written in-place into xg),
// grid.sync, EW phase (LSTM cell, writes h_buf/c_buf), grid.sync.
__global__ __launch_bounds__(256) void k_scan(const int* __restrict__ parents,
                                              const float* __restrict__ WhhT,
                                              float* __restrict__ xg,
                                              const float* __restrict__ b_hh,
                                              float* __restrict__ h_buf,
                                              float* __restrict__ c_buf,
                                              const int* __restrict__ lvl_start,
                                              const int* __restrict__ lvl_cnt,
                                              const int* __restrict__ lvl_nodes,
                                              const int* __restrict__ nlev_p) {
    cg::grid_group grid = cg::this_grid();
    const int tid = threadIdx.x;
    __shared__ float ph[4][HH];
    __shared__ int nid[4], pid[4];
    int nlev = nlev_p[0];
    if (nlev > 128) nlev = 128;
    for (int l = 0; l < nlev; ++l) {
        const int start = lvl_start[l];
        const int cnt = lvl_cnt[l];
        const int ngroups = (cnt + 3) >> 2;
        const int items = ngroups * 5;   // 5 row-chunks of 256 covering 1200 gate rows
        for (int w = blockIdx.x; w < items; w += gridDim.x) {
            const int grp = w / 5, rc = w - grp * 5;
            const int base = start + grp * 4;
            const int gc = min(4, cnt - grp * 4);
            if (tid < 4) {
                if (tid < gc) {
                    int n = lvl_nodes[base + tid];
                    nid[tid] = n;
                    pid[tid] = parents[n];
                } else {
                    nid[tid] = -1;
                    pid[tid] = -1;
                }
            }
            __syncthreads();
            for (int idx = tid; idx < 4 * HH; idx += 256) {
                int g = idx / HH, c = idx - g * HH;
                float v = 0.f;
                int n = nid[g];
                if (n >= 0) v = h_buf[((n >> 7) * 129 + pid[g] + 1) * HH + c];
                ph[g][c] = v;
            }
            __syncthreads();
            const int r = rc * 256 + tid;
            if (r < G4) {
                float a0 = 0.f, a1 = 0.f, a2 = 0.f, a3 = 0.f;
                const float* wp = WhhT + r;
#pragma unroll 4
                for (int c = 0; c < HH; ++c) {
                    float wv = wp[(size_t)c * G4];
                    a0 += wv * ph[0][c];
                    a1 += wv * ph[1][c];
                    a2 += wv * ph[2][c];
                    a3 += wv * ph[3][c];
                }
                const float bh = b_hh[r];
                if (nid[0] >= 0) xg[(size_t)nid[0] * G4 + r] += a0 + bh;
                if (nid[1] >= 0) xg[(size_t)nid[1] * G4 + r] += a1 + bh;
                if (nid[2] >= 0) xg[(size_t)nid[2] * G4 + r] += a2 + bh;
                if (nid[3] >= 0) xg[(size_t)nid[3] * G4 + r] += a3 + bh;
            }
            __syncthreads();
        }
        grid.sync();
        const int total = cnt * HH;
        for (int e = blockIdx.x * 256 + tid; e < total; e += gridDim.x * 256) {
            int gi = e / HH, u = e - gi * HH;
            int n = lvl_nodes[start + gi];
            int b = n >> 7, i = n & 127, par = parents[n];
            const float* gp = xg + (size_t)n * G4;
            float si = sigm(gp[u]);
            float sf = sigm(gp[HH + u]);
            float tg = tanh_f(gp[2 * HH + u]);
            float so = sigm(gp[3 * HH + u]);
            float pc = c_buf[(b * 129 + par + 1) * HH + u];
            float cc = sf * pc + si * tg;
            float hh = so * tanh_f(cc);
            c_buf[(b * 129 + i + 1) * HH + u] = cc;
            h_buf[(b * 129 + i + 1) * HH + u] = hh;
        }
        grid.sync();
    }
}

// cast hs -> bf16 [4096][320] (zero-padded K), W_out -> bf16 [32000][320]
__global__ void k_cast_A(const float* __restrict__ h_buf, u16* __restrict__ A) {
    for (int e = blockIdx.x * blockDim.x + threadIdx.x; e < NB * NN * KP;
         e += gridDim.x * blockDim.x) {
        int n = e / KP, k = e - n * KP;
        float v = 0.f;
        if (k < HH) v = h_buf[((n >> 7) * 129 + (n & 127) + 1) * HH + k];
        __hip_bfloat16 b = __float2bfloat16(v);
        A[e] = *reinterpret_cast<u16*>(&b);
    }
}

__global__ void k_cast_B(const float* __restrict__ W_out, u16* __restrict__ Bm) {
    for (int e = blockIdx.x * blockDim.x + threadIdx.x; e < NV * KP;
         e += gridDim.x * blockDim.x) {
        int v = e / KP, k = e - v * KP;
        float x = (k < HH) ? W_out[v * HH + k] : 0.f;
        __hip_bfloat16 b = __float2bfloat16(x);
        Bm[e] = *reinterpret_cast<u16*>(&b);
    }
}

// logits[4096][32000] = A[4096][320](bf16) @ B[32000][320](bf16)^T + b_out, fp32 accum
// 128x128 tile, BK=32, 4 waves (2x2 quadrants of 64x64), 16x16x32 bf16 MFMA
__global__ __launch_bounds__(256) void k_gemm(const u16* __restrict__ Abf,
                                              const u16* __restrict__ Bbf,
                                              const float* __restrict__ b_out,
                                              float* __restrict__ out) {
    __shared__ __align__(16) u16 As[128 * 40];
    __shared__ __align__(16) u16 Bs[128 * 40];
    const int tid = threadIdx.x;
    const int lane = tid & 63, wv = tid >> 6;
    const int wm = wv >> 1, wn = wv & 1;
    const int mblk = blockIdx.y, nblk = blockIdx.x;
    const u16* Ag = Abf + (size_t)mblk * 128 * KP;
    const u16* Bg = Bbf + (size_t)nblk * 128 * KP;
    f32x4 acc[4][4] = {};
    const int lrow = lane & 15, lseg = lane >> 4;
    for (int kk = 0; kk < KP; kk += 32) {
#pragma unroll
        for (int q = 0; q < 2; ++q) {
            int s = tid + q * 256;       // 0..511
            int r = s >> 2, seg = s & 3; // 128 rows x 4 16B-segments
            *(uint4*)&As[r * 40 + seg * 8] = *(const uint4*)&Ag[r * KP + kk + seg * 8];
            *(uint4*)&Bs[r * 40 + seg * 8] = *(const uint4*)&Bg[r * KP + kk + seg * 8];
        }
        __syncthreads();
        short8 av[4], bv[4];
#pragma unroll
        for (int i = 0; i < 4; ++i) {
            av[i] = *(const short8*)&As[(wm * 64 + i * 16 + lrow) * 40 + lseg * 8];
            bv[i] = *(const short8*)&Bs[(wn * 64 + i * 16 + lrow) * 40 + lseg * 8];
        }
#pragma unroll
        for (int i = 0; i < 4; ++i)
#pragma unroll
            for (int j = 0; j < 4; ++j)
                acc[i][j] = __builtin_amdgcn_mfma_f32_16x16x32_bf16(av[i], bv[j], acc[i][j],
                                                                    0, 0, 0);
        __syncthreads();
    }
    // C/D layout: col = lane&15, row = (lane>>4)*4 + reg  [HW-verified]
#pragma unroll
    for (int j = 0; j < 4; ++j) {
        int col = nblk * 128 + wn * 64 + j * 16 + lrow;
        float bo = b_out[col];
#pragma unroll
        for (int i = 0; i < 4; ++i) {
            int row0 = mblk * 128 + wm * 64 + i * 16 + lseg * 4;
#pragma unroll
            for (int q = 0; q < 4; ++q) {
                out[(size_t)(row0 + q) * NV + col] = acc[i][j][q] + bo;
            }
        }
    }
}

extern "C" void kernel_launch(void* const* d_in, const int* in_sizes, int n_in,
                              void* d_out, int out_size, void* d_ws, size_t ws_size,
                              hipStream_t stream) {
    const float* root_hidden = (const float*)d_in[0];
    const int* relations = (const int*)d_in[1];
    const int* prev_words = (const int*)d_in[2];
    const int* parents = (const int*)d_in[3];
    const float* emb = (const float*)d_in[4];
    const float* rel_emb = (const float*)d_in[5];
    const float* W_ih = (const float*)d_in[6];
    const float* W_hh = (const float*)d_in[7];
    const float* b_ih = (const float*)d_in[8];
    const float* b_hh = (const float*)d_in[9];
    const float* W_out = (const float*)d_in[10];
    const float* b_out = (const float*)d_in[11];
    float* out = (float*)d_out;

    float* WihT = (float*)d_ws;                  // 420000 f32
    float* WhhT = WihT + 420000;                 // 360000 f32
    float* xg = WhhT + 360000;                   // 4915200 f32
    float* h_buf = xg + 4915200;                 // 1238400 f32
    float* c_buf = h_buf + 1238400;              // 1238400 f32
    u16* Abf = (u16*)(c_buf + 1238400);          // 1310720 u16
    u16* Bbf = Abf + 1310720;                    // 10240000 u16
    int* depth = (int*)(Bbf + 10240000);         // 4096 i32
    int* lvl_start = depth + 4096;               // 128 i32
    int* lvl_cnt = lvl_start + 128;              // 128 i32
    int* lvl_nodes = lvl_cnt + 128;              // 4096 i32
    int* nlev = lvl_nodes + 4096;                // 1 i32

    k_init_roots<<<(NB * HH + 255) / 256, 256, 0, stream>>>(root_hidden, h_buf, c_buf);
    k_transpose<<<2048, 256, 0, stream>>>(W_ih, W_hh, WihT, WhhT);
    k_xg<<<NB * NN / 8, 256, 0, stream>>>(relations, prev_words, rel_emb, emb, WihT, b_ih, xg);
    k_levels<<<1, 1024, 0, stream>>>(parents, depth, lvl_start, lvl_cnt, lvl_nodes, nlev);

    void* args[] = {(void*)&parents, (void*)&WhhT, (void*)&xg, (void*)&b_hh,
                    (void*)&h_buf, (void*)&c_buf, (void*)&lvl_start, (void*)&lvl_cnt,
                    (void*)&lvl_nodes, (void*)&nlev};
    hipLaunchCooperativeKernel((const void*)k_scan, dim3(512), dim3(256), args, 0, stream);

    k_cast_A<<<2048, 256, 0, stream>>>(h_buf, Abf);
    k_cast_B<<<4096, 256, 0, stream>>>(W_out, Bbf);
    k_gemm<<<dim3(NV / 128, NB * NN / 128), 256, 0, stream>>>(Abf, Bbf, b_out, out);
}

// Round 2
// 1113.162 us; speedup vs baseline: 1.8473x; 1.8473x over previous
//
#include <hip/hip_runtime.h>
#include <hip/hip_bf16.h>
#include <hip/hip_cooperative_groups.h>

typedef unsigned short u16;
typedef __attribute__((ext_vector_type(8))) short short8;
typedef __attribute__((ext_vector_type(4))) float f32x4;

#define NB 32      // trees
#define NN 128     // nodes per tree
#define HH 300     // hidden
#define G4 1200    // 4*H
#define NV 32000   // vocab
#define INW 350    // RD+E
#define KP 320     // padded K for MFMA (300 -> 320)
#define WPAD 1280  // padded gate-row count (1200 -> 1280), pad rows are zero
#define NBLK 512   // persistent scan blocks; 512*8 == 4096 nodes

__device__ __forceinline__ float sigm(float x) { return 1.f / (1.f + __expf(-x)); }
__device__ __forceinline__ float tanh_f(float x) {
    float e = __expf(2.f * x);
    return 1.f - 2.f / (e + 1.f);
}

// h_buf/c_buf layout: [B][129][H]; slot 0 = root state
__global__ void k_init_roots(const float* __restrict__ rh, float* __restrict__ h_buf,
                             float* __restrict__ c_buf) {
    int n = blockIdx.x * blockDim.x + threadIdx.x;
    if (n < NB * HH) {
        int b = n / HH, u = n - b * HH;
        float v = rh[n];
        h_buf[(b * 129) * HH + u] = v;
        c_buf[(b * 129) * HH + u] = v;
    }
}

// WihT [350][1200]; WhhT [300][1280] zero-padded rows >= 1200
__global__ void k_transpose(const float* __restrict__ W_ih, const float* __restrict__ W_hh,
                            float* __restrict__ WihT, float* __restrict__ WhhT) {
    const int tot = INW * G4 + HH * WPAD;
    for (int n = blockIdx.x * blockDim.x + threadIdx.x; n < tot; n += gridDim.x * blockDim.x) {
        if (n < INW * G4) {
            int c = n / G4, r = n - c * G4;
            WihT[n] = W_ih[r * INW + c];
        } else {
            int m = n - INW * G4;
            int c = m / WPAD, r = m - c * WPAD;
            WhhT[m] = (r < G4) ? W_hh[r * HH + c] : 0.f;
        }
    }
}

// xg[node][1200] = concat(rel_emb[rel], emb[word]) @ W_ih^T + b_ih
__global__ __launch_bounds__(256) void k_xg(const int* __restrict__ relations,
                                            const int* __restrict__ prev_words,
                                            const float* __restrict__ rel_emb,
                                            const float* __restrict__ emb,
                                            const float* __restrict__ WihT,
                                            const float* __restrict__ b_ih,
                                            float* __restrict__ xg) {
    __shared__ float xl[8][INW];
    __shared__ int rid[8], wid[8];
    const int tid = threadIdx.x;
    const int nb = blockIdx.x * 8;
    if (tid < 8) { rid[tid] = relations[nb + tid]; wid[tid] = prev_words[nb + tid]; }
    __syncthreads();
    for (int idx = tid; idx < 8 * INW; idx += 256) {
        int g = idx / INW, c = idx - g * INW;
        xl[g][c] = (c < 50) ? rel_emb[rid[g] * 50 + c] : emb[wid[g] * HH + (c - 50)];
    }
    __syncthreads();
    for (int k = 0; k < 5; ++k) {
        int r = k * 256 + tid;
        if (r >= G4) break;
        float acc[8] = {0.f, 0.f, 0.f, 0.f, 0.f, 0.f, 0.f, 0.f};
        for (int c = 0; c < INW; ++c) {
            float wv = WihT[(size_t)c * G4 + r];
#pragma unroll
            for (int g = 0; g < 8; ++g) acc[g] += wv * xl[g][c];
        }
        float bi = b_ih[r];
#pragma unroll
        for (int g = 0; g < 8; ++g) xg[(size_t)(nb + g) * G4 + r] = acc[g] + bi;
    }
}

// Build child adjacency (kstart/kids), reset queue, enqueue roots.
// Runs every launch -> deterministic state for graph replay.
__global__ __launch_bounds__(1024) void k_prep(const int* __restrict__ parents,
                                               int* __restrict__ ready,
                                               int* __restrict__ qtail,
                                               int* __restrict__ kstart,
                                               int* __restrict__ kids) {
    __shared__ int cnt_s[4096];
    __shared__ int pfx_s[4096];
    __shared__ int part_s[64];
    __shared__ int rc_s;
    const int tid = threadIdx.x;
    for (int n = tid; n < NB * NN; n += 1024) { cnt_s[n] = 0; ready[n] = -1; }
    if (tid == 0) rc_s = 0;
    __syncthreads();
    for (int n = tid; n < NB * NN; n += 1024) {
        int p = parents[n];
        if (p >= 0) atomicAdd(&cnt_s[(n & ~127) + p], 1);
    }
    __syncthreads();
    if (tid < 64) {
        int s = 0;
        for (int k = 0; k < 64; ++k) { int t = cnt_s[tid * 64 + k]; pfx_s[tid * 64 + k] = s; s += t; }
        part_s[tid] = s;
    }
    __syncthreads();
    if (tid == 0) {
        int s = 0;
        for (int k = 0; k < 64; ++k) { int t = part_s[k]; part_s[k] = s; s += t; }
        kstart[4096] = s;
    }
    __syncthreads();
    if (tid < 64) {
        int off = part_s[tid];
        for (int k = 0; k < 64; ++k) pfx_s[tid * 64 + k] += off;
    }
    __syncthreads();
    for (int n = tid; n < NB * NN; n += 1024) kstart[n] = pfx_s[n];
    __syncthreads();
    for (int n = tid; n < NB * NN; n += 1024) {
        int p = parents[n];
        if (p >= 0) {
            int pos = atomicAdd(&pfx_s[(n & ~127) + p], 1);
            kids[pos] = n;
        } else {
            int slot = atomicAdd(&rc_s, 1);
            ready[slot] = n;  // kernel-boundary release makes this visible to k_scan_df
        }
    }
    __syncthreads();
    if (tid == 0) qtail[0] = rc_s;
}

// One sub-batch of G ready nodes: gates = xg + W_hh @ h_parent + b_hh; LSTM cell.
template <int G>
__device__ __forceinline__ void do_chunk(const int* __restrict__ ids,
                                         const int* __restrict__ parents,
                                         const float* __restrict__ WhhT,
                                         const float* __restrict__ xg,
                                         const float* __restrict__ b_hh,
                                         float* __restrict__ h_buf,
                                         float* __restrict__ c_buf,
                                         float* __restrict__ phT,    // [300][8]
                                         float* __restrict__ gates,  // [8][1280]
                                         int tid) {
    // stage parent h into LDS (transposed [c][j])
    for (int e = tid; e < G * HH; e += 256) {
        int j = e / HH, c = e - j * HH;
        int n = ids[j];
        int p = parents[n];
        int b = n >> 7;
        phT[c * 8 + j] = h_buf[(size_t)(b * 129 + p + 1) * HH + c];
    }
    __syncthreads();

    float acc0[G], acc1[G], acc2[G], acc3[G], acc4[G];
#pragma unroll
    for (int j = 0; j < G; ++j) acc0[j] = acc1[j] = acc2[j] = acc3[j] = acc4[j] = 0.f;

    const float* wbase = WhhT + tid;
#pragma unroll 2
    for (int c = 0; c < HH; ++c) {
        const float* wp = wbase + c * WPAD;
        float w0 = wp[0], w1 = wp[256], w2 = wp[512], w3 = wp[768], w4 = wp[1024];
        float pv[G];
        if constexpr (G == 8) {
            f32x4 a = *(const f32x4*)&phT[c * 8];
            f32x4 b2 = *(const f32x4*)&phT[c * 8 + 4];
            pv[0] = a[0]; pv[1] = a[1]; pv[2] = a[2]; pv[3] = a[3];
            pv[4] = b2[0]; pv[5] = b2[1]; pv[6] = b2[2]; pv[7] = b2[3];
        } else if constexpr (G == 4) {
            f32x4 a = *(const f32x4*)&phT[c * 8];
            pv[0] = a[0]; pv[1] = a[1]; pv[2] = a[2]; pv[3] = a[3];
        } else if constexpr (G == 2) {
            pv[0] = phT[c * 8]; pv[1] = phT[c * 8 + 1];
        } else {
            pv[0] = phT[c * 8];
        }
#pragma unroll
        for (int j = 0; j < G; ++j) {
            acc0[j] = fmaf(w0, pv[j], acc0[j]);
            acc1[j] = fmaf(w1, pv[j], acc1[j]);
            acc2[j] = fmaf(w2, pv[j], acc2[j]);
            acc3[j] = fmaf(w3, pv[j], acc3[j]);
            acc4[j] = fmaf(w4, pv[j], acc4[j]);
        }
    }
    const int r4 = 1024 + tid;
#pragma unroll
    for (int j = 0; j < G; ++j) {
        int n = ids[j];
        const float* xgp = xg + (size_t)n * G4;
        float* gp = gates + j * WPAD;
        gp[tid] = acc0[j] + xgp[tid] + b_hh[tid];
        gp[tid + 256] = acc1[j] + xgp[tid + 256] + b_hh[tid + 256];
        gp[tid + 512] = acc2[j] + xgp[tid + 512] + b_hh[tid + 512];
        gp[tid + 768] = acc3[j] + xgp[tid + 768] + b_hh[tid + 768];
        if (tid < G4 - 1024)
            gp[r4] = acc4[j] + xgp[r4] + b_hh[r4];
    }
    __syncthreads();
    // LSTM cell elementwise
    for (int e = tid; e < G * HH; e += 256) {
        int j = e / HH, u = e - j * HH;
        int n = ids[j];
        int b = n >> 7, i = n & 127, p = parents[n];
        const float* gp = gates + j * WPAD;
        float gi = gp[u], gf = gp[HH + u], gg = gp[2 * HH + u], go = gp[3 * HH + u];
        float pc = c_buf[(size_t)(b * 129 + p + 1) * HH + u];
        float cc = sigm(gf) * pc + sigm(gi) * tanh_f(gg);
        float hh = sigm(go) * tanh_f(cc);
        c_buf[(size_t)(b * 129 + i + 1) * HH + u] = cc;
        h_buf[(size_t)(b * 129 + i + 1) * HH + u] = hh;
    }
    __syncthreads();  // drains each thread's global stores (vmcnt) before leader's release
}

// Dataflow LSTM scan: persistent cooperative grid, no grid.sync.
// Block b owns queue slots [8b, 8b+8). Dependencies flow low slot -> high slot,
// ranges are disjoint, filled-prefix processing => deadlock-free.
__global__ __launch_bounds__(256) void k_scan_df(const int* __restrict__ parents,
                                                 const float* __restrict__ WhhT,
                                                 const float* __restrict__ xg,
                                                 const float* __restrict__ b_hh,
                                                 float* __restrict__ h_buf,
                                                 float* __restrict__ c_buf,
                                                 int* __restrict__ ready,
                                                 int* __restrict__ qtail,
                                                 const int* __restrict__ kstart,
                                                 const int* __restrict__ kids) {
    __shared__ float phT_s[HH * 8];
    __shared__ float gates_s[8 * WPAD];
    __shared__ int ids_s[8];
    __shared__ int g_s;
    const int tid = threadIdx.x;
    const int base = blockIdx.x * 8;
    int got = 0;
    while (got < 8) {
        if (tid == 0) {
            int v;
            while ((v = __hip_atomic_load(&ready[base + got], __ATOMIC_RELAXED,
                                          __HIP_MEMORY_SCOPE_AGENT)) < 0)
                __builtin_amdgcn_s_sleep(8);
            ids_s[0] = v;
            int avail = 1;
            while (got + avail < 8) {
                int u = __hip_atomic_load(&ready[base + got + avail], __ATOMIC_RELAXED,
                                          __HIP_MEMORY_SCOPE_AGENT);
                if (u < 0) break;
                ids_s[avail] = u;
                ++avail;
            }
            g_s = avail >= 8 ? 8 : avail >= 4 ? 4 : avail >= 2 ? 2 : 1;
            __threadfence();  // acquire: invalidate stale cached h/c before block reads them
        }
        __syncthreads();
        const int g = g_s;
        switch (g) {
            case 8: do_chunk<8>(ids_s, parents, WhhT, xg, b_hh, h_buf, c_buf, phT_s, gates_s, tid); break;
            case 4: do_chunk<4>(ids_s, parents, WhhT, xg, b_hh, h_buf, c_buf, phT_s, gates_s, tid); break;
            case 2: do_chunk<2>(ids_s, parents, WhhT, xg, b_hh, h_buf, c_buf, phT_s, gates_s, tid); break;
            default: do_chunk<1>(ids_s, parents, WhhT, xg, b_hh, h_buf, c_buf, phT_s, gates_s, tid); break;
        }
        if (tid == 0) {
            __threadfence();  // release: h/c stores visible device-wide before publishing kids
            for (int j = 0; j < g; ++j) {
                int n = ids_s[j];
                int ks = kstart[n], ke = kstart[n + 1];
                for (int q = ks; q < ke; ++q) {
                    int kid = kids[q];
                    int slot = atomicAdd(qtail, 1);
                    __hip_atomic_store(&ready[slot], kid, __ATOMIC_RELAXED,
                                       __HIP_MEMORY_SCOPE_AGENT);
                }
            }
        }
        got += g;
        __syncthreads();
    }
}

// cast hs -> bf16 [4096][320] (zero-padded K), W_out -> bf16 [32000][320]
__global__ void k_cast_A(const float* __restrict__ h_buf, u16* __restrict__ A) {
    for (int e = blockIdx.x * blockDim.x + threadIdx.x; e < NB * NN * KP;
         e += gridDim.x * blockDim.x) {
        int n = e / KP, k = e - n * KP;
        float v = 0.f;
        if (k < HH) v = h_buf[((n >> 7) * 129 + (n & 127) + 1) * HH + k];
        __hip_bfloat16 b = __float2bfloat16(v);
        A[e] = *reinterpret_cast<u16*>(&b);
    }
}

__global__ void k_cast_B(const float* __restrict__ W_out, u16* __restrict__ Bm) {
    for (int e = blockIdx.x * blockDim.x + threadIdx.x; e < NV * KP;
         e += gridDim.x * blockDim.x) {
        int v = e / KP, k = e - v * KP;
        float x = (k < HH) ? W_out[v * HH + k] : 0.f;
        __hip_bfloat16 b = __float2bfloat16(x);
        Bm[e] = *reinterpret_cast<u16*>(&b);
    }
}

// logits[4096][32000] = A(bf16) @ B(bf16)^T + b_out, fp32 accum.
// grid = (M/128, N/128): consecutive blocks share one B tile, A stays L2-resident.
__global__ __launch_bounds__(256) void k_gemm(const u16* __restrict__ Abf,
                                              const u16* __restrict__ Bbf,
                                              const float* __restrict__ b_out,
                                              float* __restrict__ out) {
    __shared__ __align__(16) u16 As[128 * 40];
    __shared__ __align__(16) u16 Bs[128 * 40];
    const int tid = threadIdx.x;
    const int lane = tid & 63, wv = tid >> 6;
    const int wm = wv >> 1, wn = wv & 1;
    const int mblk = blockIdx.x, nblk = blockIdx.y;
    const u16* Ag = Abf + (size_t)mblk * 128 * KP;
    const u16* Bg = Bbf + (size_t)nblk * 128 * KP;
    f32x4 acc[4][4] = {};
    const int lrow = lane & 15, lseg = lane >> 4;
    for (int kk = 0; kk < KP; kk += 32) {
#pragma unroll
        for (int q = 0; q < 2; ++q) {
            int s = tid + q * 256;
            int r = s >> 2, seg = s & 3;
            *(uint4*)&As[r * 40 + seg * 8] = *(const uint4*)&Ag[r * KP + kk + seg * 8];
            *(uint4*)&Bs[r * 40 + seg * 8] = *(const uint4*)&Bg[r * KP + kk + seg * 8];
        }
        __syncthreads();
        short8 av[4], bv[4];
#pragma unroll
        for (int i = 0; i < 4; ++i) {
            av[i] = *(const short8*)&As[(wm * 64 + i * 16 + lrow) * 40 + lseg * 8];
            bv[i] = *(const short8*)&Bs[(wn * 64 + i * 16 + lrow) * 40 + lseg * 8];
        }
#pragma unroll
        for (int i = 0; i < 4; ++i)
#pragma unroll
            for (int j = 0; j < 4; ++j)
                acc[i][j] = __builtin_amdgcn_mfma_f32_16x16x32_bf16(av[i], bv[j], acc[i][j],
                                                                    0, 0, 0);
        __syncthreads();
    }
#pragma unroll
    for (int j = 0; j < 4; ++j) {
        int col = nblk * 128 + wn * 64 + j * 16 + lrow;
        float bo = b_out[col];
#pragma unroll
        for (int i = 0; i < 4; ++i) {
            int row0 = mblk * 128 + wm * 64 + i * 16 + lseg * 4;
#pragma unroll
            for (int q = 0; q < 4; ++q) {
                out[(size_t)(row0 + q) * NV + col] = acc[i][j][q] + bo;
            }
        }
    }
}

extern "C" void kernel_launch(void* const* d_in, const int* in_sizes, int n_in,
                              void* d_out, int out_size, void* d_ws, size_t ws_size,
                              hipStream_t stream) {
    const float* root_hidden = (const float*)d_in[0];
    const int* relations = (const int*)d_in[1];
    const int* prev_words = (const int*)d_in[2];
    const int* parents = (const int*)d_in[3];
    const float* emb = (const float*)d_in[4];
    const float* rel_emb = (const float*)d_in[5];
    const float* W_ih = (const float*)d_in[6];
    const float* W_hh = (const float*)d_in[7];
    const float* b_ih = (const float*)d_in[8];
    const float* b_hh = (const float*)d_in[9];
    const float* W_out = (const float*)d_in[10];
    const float* b_out = (const float*)d_in[11];
    float* out = (float*)d_out;

    float* WihT = (float*)d_ws;                  // 420000 f32
    float* WhhT = WihT + 420000;                 // 384000 f32 (300 x 1280, zero-padded)
    float* xg = WhhT + 384000;                   // 4915200 f32
    float* h_buf = xg + 4915200;                 // 1238400 f32
    float* c_buf = h_buf + 1238400;              // 1238400 f32
    u16* Abf = (u16*)(c_buf + 1238400);          // 1310720 u16
    u16* Bbf = Abf + 1310720;                    // 10240000 u16
    int* ready = (int*)(Bbf + 10240000);         // 4096 i32
    int* qtail = ready + 4096;                   // 16 i32 (padded)
    int* kstart = qtail + 16;                    // 4097 i32
    int* kids = kstart + 4097;                   // 4096 i32

    k_init_roots<<<(NB * HH + 255) / 256, 256, 0, stream>>>(root_hidden, h_buf, c_buf);
    k_transpose<<<2048, 256, 0, stream>>>(W_ih, W_hh, WihT, WhhT);
    k_xg<<<NB * NN / 8, 256, 0, stream>>>(relations, prev_words, rel_emb, emb, WihT, b_ih, xg);
    k_prep<<<1, 1024, 0, stream>>>(parents, ready, qtail, kstart, kids);

    void* args[] = {(void*)&parents, (void*)&WhhT, (void*)&xg, (void*)&b_hh,
                    (void*)&h_buf, (void*)&c_buf, (void*)&ready, (void*)&qtail,
                    (void*)&kstart, (void*)&kids};
    hipLaunchCooperativeKernel((const void*)k_scan_df, dim3(NBLK), dim3(256), args, 0, stream);

    k_cast_A<<<2048, 256, 0, stream>>>(h_buf, Abf);
    k_cast_B<<<4096, 256, 0, stream>>>(W_out, Bbf);
    k_gemm<<<dim3(NB * NN / 128, NV / 128), 256, 0, stream>>>(Abf, Bbf, b_out, out);
}